// Round 5
// baseline (384.320 us; speedup 1.0000x reference)
//
#include <hip/hip_runtime.h>

#define C_N   512
#define E_N   261632

typedef _Float16 f16;
typedef _Float16 f16x8_t __attribute__((ext_vector_type(8)));
typedef float    f32x16_t __attribute__((ext_vector_type(16)));

// ---------------- fused prep: precompute SA/RB + pack W2 + hist partials ----------------
// blocks [0,256): SA/RB precompute; [256,384): pack W2 (32x32x16 B-frag order); [384,448): hist partials
__global__ __launch_bounds__(256) void k_prep(const float* __restrict__ inputs,
    const float* __restrict__ W1, const float* __restrict__ b1,
    const float* __restrict__ W2, const int* __restrict__ rec,
    f16* __restrict__ SA, f16* __restrict__ RB, f16* __restrict__ W2p,
    int* __restrict__ hist_part)
{
  int bid = blockIdx.x;
  if (bid < 256) {
    int t  = bid >> 7;
    int c0 = (bid & 127) * 4;
    __shared__ float xs[4][256];
    for (int i = threadIdx.x; i < 1024; i += 256)
      xs[i >> 8][i & 255] = inputs[(size_t)(c0 + (i >> 8)) * 256 + (i & 255)];
    __syncthreads();
    const float* W1t = W1 + (size_t)t * 512 * 512;
    int h0 = threadIdx.x;
    float sa[2][4] = {{0.f}}, rbv[2][4] = {{0.f}};
    for (int d = 0; d < 256; d++) {
      float wt0 = W1t[d * 512 + h0];
      float wt1 = W1t[d * 512 + h0 + 256];
      float wb0 = W1t[(256 + d) * 512 + h0];
      float wb1 = W1t[(256 + d) * 512 + h0 + 256];
      #pragma unroll
      for (int r = 0; r < 4; r++) {
        float x = xs[r][d];
        sa[0][r]  += x * wt0; sa[1][r]  += x * wt1;
        rbv[0][r] += x * wb0; rbv[1][r] += x * wb1;
      }
    }
    #pragma unroll
    for (int hh = 0; hh < 2; hh++) {
      int h = h0 + hh * 256;
      float bb = b1[t * 512 + h];
      #pragma unroll
      for (int r = 0; r < 4; r++) {
        SA[((size_t)(t * 512 + c0 + r)) * 512 + h] = (f16)sa[hh][r];
        RB[((size_t)(t * 512 + c0 + r)) * 512 + h] = (f16)(rbv[hh][r] + bb);
      }
    }
  } else if (bid < 384) {
    // B-frag for mfma_f32_32x32x16_f16: B[k][n], n=lane&31, k=kc*16+(lane>>5)*8+j
    int gid  = (bid - 256) * 256 + threadIdx.x;   // 0..32767
    int lane = gid & 63;
    int ct   = (gid >> 6) & 7;     // 8 col-tiles of 32
    int kc   = (gid >> 9) & 31;    // 32 k-steps of 16
    int t    = gid >> 14;
    int n    = ct * 32 + (lane & 31);
    int k0   = kc * 16 + (lane >> 5) * 8;
    const float* src = W2 + (size_t)t * 512 * 256;
    f16x8_t v;
    #pragma unroll
    for (int j = 0; j < 8; j++) v[j] = (f16)src[(size_t)(k0 + j) * 256 + n];
    *(f16x8_t*)(W2p + (size_t)gid * 8) = v;
  } else {
    int hb = bid - 384;                 // 0..63
    __shared__ int lh[512];
    for (int i = threadIdx.x; i < 512; i += 256) lh[i] = 0;
    __syncthreads();
    int e0 = hb * (E_N / 64);           // 4088 exactly
    for (int i = threadIdx.x; i < E_N / 64; i += 256)
      atomicAdd(&lh[rec[e0 + i]], 1);
    __syncthreads();
    for (int i = threadIdx.x; i < 512; i += 256)
      hist_part[hb * 512 + i] = lh[i];
  }
}

// ---------------- scan: totals + exclusive scan + per-scatter-block bases ----------------
__global__ void k_scan(const int* __restrict__ hist_part, int* __restrict__ seg,
                       int* __restrict__ base)
{
  __shared__ int s[512];
  int tid = threadIdx.x;
  int tot = 0;
  #pragma unroll 8
  for (int b = 0; b < 64; b++) tot += hist_part[b * 512 + tid];
  s[tid] = tot;
  __syncthreads();
  for (int off = 1; off < 512; off <<= 1) {
    int v = (tid >= off) ? s[tid - off] : 0;
    __syncthreads();
    s[tid] += v;
    __syncthreads();
  }
  int excl = s[tid] - tot;
  seg[tid] = excl;
  if (tid == 0) seg[512] = E_N;
  int run = excl;
  for (int b = 0; b < 64; b++) {
    base[b * 512 + tid] = run;
    run += hist_part[b * 512 + tid];
  }
}

// ---------------- scatter: no global atomics; writes pre-gathered metadata ----------------
__global__ __launch_bounds__(1024) void k_scatter3(const int* __restrict__ rec,
    const int* __restrict__ send, const float* __restrict__ rel,
    const int* __restrict__ base, int* __restrict__ ssend, float2* __restrict__ srel)
{
  __shared__ int lh[512];
  __shared__ int lb[512];
  int b = blockIdx.x;
  int e0 = b * (E_N / 64);   // 4088 exactly
  for (int i = threadIdx.x; i < 512; i += 1024) { lh[i] = 0; lb[i] = base[b * 512 + i]; }
  __syncthreads();
  for (int i = threadIdx.x; i < E_N / 64; i += 1024) {
    int e = e0 + i;
    int r = rec[e];
    int p = lb[r] + atomicAdd(&lh[r], 1);
    ssend[p] = send[e];
    srel[p]  = make_float2(rel[2 * (size_t)e], rel[2 * (size_t)e + 1]);
  }
}

// ---------------- K5: per-receiver edge MLP + aggregation (32x32x16, pipelined) ----------------
#define H1S 520   // f16 elems per h1 row: 512 + 8 pad

__global__ __launch_bounds__(256, 2) void k_edges(
    const f16* __restrict__ SA, const f16* __restrict__ RB,
    const f16* __restrict__ W2p, const float* __restrict__ b2,
    const int* __restrict__ ssend, const float2* __restrict__ srel,
    const int* __restrict__ seg, float* __restrict__ agg)
{
  __shared__ f16   h1[64 * H1S];      // 66560 B
  __shared__ f16   rbs[2][512];       // 2048 B
  __shared__ float b2s[2][256];       // 2048 B
  __shared__ float aggL[256];         // 1024 B
  __shared__ float relv2[2][64][2];   // 1024 B
  __shared__ int   sends2[2][64];     // 512 B

  int c    = blockIdx.x;
  int tid  = threadIdx.x;             // 0..255
  int lane = tid & 63;
  int w    = tid >> 6;                // wave 0..3 -> col tiles 2w, 2w+1 (of 32)
  int hlf  = lane >> 5;               // 0..1
  int l31  = lane & 31;
  int q    = tid & 63;                // 16B chunk index in a 512-f16 row
  int rb0  = tid >> 6;                // gather/build base row: rows rb0 + 4j, j 0..15

  if (tid < 128) {
    int t = tid >> 6, qq = tid & 63;
    *(f16x8_t*)&rbs[t][qq * 8] = *(const f16x8_t*)&RB[((size_t)(t * 512 + c)) * 512 + qq * 8];
  }
  if (tid < 256) aggL[tid] = 0.0f;
  { int t = tid >> 7, col = tid & 255; b2s[t][col] = b2[t * 256 + col]; }
  { int t2 = (tid >> 7) ^ 1, col = tid & 255; b2s[t2][col] = b2[t2 * 256 + col]; }

  int s0 = seg[c], s1 = seg[c + 1];
  int nt = (s1 - s0 + 63) >> 6;

  if (nt > 0 && tid < 64) {
    int pos = s0 + tid;
    if (pos < s1) {
      sends2[0][tid] = ssend[pos];
      float2 rr = srel[pos];
      relv2[0][tid][0] = rr.x;
      relv2[0][tid][1] = rr.y;
    } else {
      sends2[0][tid] = 0; relv2[0][tid][0] = 0.f; relv2[0][tid][1] = 0.f;
    }
  }
  __syncthreads();

  f16x8_t g[16];
  const f16x8_t* SAc = (const f16x8_t*)SA;   // row r of type t at chunk (t*512+r)*64
  const f16x8_t* Bp  = (const f16x8_t*)W2p;

  if (nt > 0) {
    #pragma unroll
    for (int j = 0; j < 16; j++)
      g[j] = SAc[(size_t)sends2[0][rb0 + 4 * j] * 64 + q];
  }

  for (int ph = 0; ph < 2 * nt; ph++) {
    int ti  = ph >> 1;
    int t   = ph & 1;
    int cb  = ti & 1;
    int nb  = cb ^ 1;
    bool more = (ti + 1 < nt);

    // ---- build h1 = relu(SA[t][send] + RB[t][c]) from prefetched g ----
    {
      f16x8_t rbq = *(const f16x8_t*)&rbs[t][q * 8];
      #pragma unroll
      for (int j = 0; j < 16; j++) {
        int row = rb0 + 4 * j;
        f16x8_t hv;
        #pragma unroll
        for (int e = 0; e < 8; e++) {
          f16 v = (f16)(g[j][e] + rbq[e]);
          hv[e] = (v > (f16)0.0f) ? v : (f16)0.0f;
        }
        *(f16x8_t*)&h1[row * H1S + q * 8] = hv;
      }
    }
    __syncthreads();

    if (t == 0 && more && tid < 64) {
      int pos = s0 + (ti + 1) * 64 + tid;
      if (pos < s1) {
        sends2[nb][tid] = ssend[pos];
        float2 rr = srel[pos];
        relv2[nb][tid][0] = rr.x;
        relv2[nb][tid][1] = rr.y;
      } else {
        sends2[nb][tid] = 0; relv2[nb][tid][0] = 0.f; relv2[nb][tid][1] = 0.f;
      }
    }

    // ---- GEMM: msg[64,256] = h1 @ W2[t], 32x32x16 MFMA, 2rt x 2ct per wave ----
    f32x16_t acc[2][2];
    #pragma unroll
    for (int rt = 0; rt < 2; rt++)
      #pragma unroll
      for (int ctl = 0; ctl < 2; ctl++)
        #pragma unroll
        for (int r = 0; r < 16; r++) acc[rt][ctl][r] = 0.f;

    f16x8_t bb[2][2];
    #pragma unroll
    for (int ctl = 0; ctl < 2; ctl++)
      bb[0][ctl] = Bp[(size_t)(((t * 32 + 0) * 8 + (2 * w + ctl)) * 64 + lane)];
    #pragma unroll
    for (int ctl = 0; ctl < 2; ctl++)
      bb[1][ctl] = Bp[(size_t)(((t * 32 + 1) * 8 + (2 * w + ctl)) * 64 + lane)];

    // cross-phase gather issued after first B loads (stays in flight across kc loop)
    if (t == 0) {
      #pragma unroll
      for (int j = 0; j < 16; j++)
        g[j] = SAc[(size_t)(512 + sends2[cb][rb0 + 4 * j]) * 64 + q];
    } else if (more) {
      #pragma unroll
      for (int j = 0; j < 16; j++)
        g[j] = SAc[(size_t)sends2[nb][rb0 + 4 * j] * 64 + q];
    }

    for (int kc = 0; kc < 32; kc++) {
      int pb = kc & 1;
      #pragma unroll
      for (int rt = 0; rt < 2; rt++) {
        // A-frag: A[m][k], m=lane&31, k=(lane>>5)*8+j  -> row rt*32+l31, f16 ofs kc*16+hlf*8
        f16x8_t af = *(const f16x8_t*)&h1[(rt * 32 + l31) * H1S + kc * 16 + hlf * 8];
        #pragma unroll
        for (int ctl = 0; ctl < 2; ctl++)
          acc[rt][ctl] = __builtin_amdgcn_mfma_f32_32x32x16_f16(af, bb[pb][ctl], acc[rt][ctl], 0, 0, 0);
      }
      if (kc + 2 < 32) {
        #pragma unroll
        for (int ctl = 0; ctl < 2; ctl++)
          bb[pb][ctl] = Bp[(size_t)(((t * 32 + kc + 2) * 8 + (2 * w + ctl)) * 64 + lane)];
      }
    }

    // ---- epilogue: +b2, relu, *rel_type, reduce rows -> aggL ----
    // C/D 32x32: col = lane&31, row = (reg&3) + 8*(reg>>2) + 4*(lane>>5)
    #pragma unroll
    for (int ctl = 0; ctl < 2; ctl++) {
      int col = (2 * w + ctl) * 32 + l31;
      float b2c = b2s[t][col];
      float csum = 0.0f;
      #pragma unroll
      for (int rt = 0; rt < 2; rt++)
        #pragma unroll
        for (int r = 0; r < 16; r++) {
          int row = rt * 32 + (r & 3) + 8 * (r >> 2) + 4 * hlf;
          float v = fmaxf(acc[rt][ctl][r] + b2c, 0.0f);
          csum += v * relv2[cb][row][t];
        }
      csum += __shfl_xor(csum, 32, 64);
      if (hlf == 0) aggL[col] += csum;   // waves own disjoint col ranges
    }
    __syncthreads();
  }

  agg[(size_t)c * 256 + tid] = aggL[tid];
}

// ---------------- K6: output MLP (2 rows per block, fp32) ----------------
__global__ __launch_bounds__(256) void k_out_mlp(const float* __restrict__ agg,
    const float* __restrict__ Wo1, const float* __restrict__ bo1,
    const float* __restrict__ Wo2, const float* __restrict__ bo2,
    const float* __restrict__ Wo3, const float* __restrict__ bo3,
    float* __restrict__ out)
{
  __shared__ float xs[2][256];
  __shared__ float h1s[2][512];
  __shared__ float h2s[2][512];
  int tid = threadIdx.x;
  int c0 = blockIdx.x * 2;
  for (int i = tid; i < 512; i += 256)
    xs[i >> 8][i & 255] = agg[(size_t)(c0 + (i >> 8)) * 256 + (i & 255)];
  __syncthreads();
  #pragma unroll
  for (int hh = 0; hh < 2; hh++) {
    int h = tid + hh * 256;
    float a0 = 0.f, a1 = 0.f;
    for (int m = 0; m < 256; m++) {
      float wv = Wo1[m * 512 + h];
      a0 += xs[0][m] * wv;
      a1 += xs[1][m] * wv;
    }
    float bb = bo1[h];
    h1s[0][h] = fmaxf(a0 + bb, 0.f);
    h1s[1][h] = fmaxf(a1 + bb, 0.f);
  }
  __syncthreads();
  #pragma unroll
  for (int hh = 0; hh < 2; hh++) {
    int h = tid + hh * 256;
    float a0 = 0.f, a1 = 0.f;
    for (int m = 0; m < 512; m++) {
      float wv = Wo2[m * 512 + h];
      a0 += h1s[0][m] * wv;
      a1 += h1s[1][m] * wv;
    }
    float bb = bo2[h];
    h2s[0][h] = fmaxf(a0 + bb, 0.f);
    h2s[1][h] = fmaxf(a1 + bb, 0.f);
  }
  __syncthreads();
  {
    int d = tid;
    float a0 = 0.f, a1 = 0.f;
    for (int m = 0; m < 512; m++) {
      float wv = Wo3[m * 256 + d];
      a0 += h2s[0][m] * wv;
      a1 += h2s[1][m] * wv;
    }
    out[(size_t)c0 * 256 + d]       = a0 + bo3[d];
    out[((size_t)c0 + 1) * 256 + d] = a1 + bo3[d];
  }
}

// ---------------- launcher ----------------
extern "C" void kernel_launch(void* const* d_in, const int* in_sizes, int n_in,
                              void* d_out, int out_size, void* d_ws, size_t ws_size,
                              hipStream_t stream)
{
  (void)in_sizes; (void)n_in; (void)out_size; (void)ws_size;
  const float* inputs = (const float*)d_in[0];
  const float* rel    = (const float*)d_in[1];
  const float* W1     = (const float*)d_in[2];
  const float* b1     = (const float*)d_in[3];
  const float* W2     = (const float*)d_in[4];
  const float* b2     = (const float*)d_in[5];
  const float* Wo1    = (const float*)d_in[6];
  const float* bo1    = (const float*)d_in[7];
  const float* Wo2    = (const float*)d_in[8];
  const float* bo2    = (const float*)d_in[9];
  const float* Wo3    = (const float*)d_in[10];
  const float* bo3    = (const float*)d_in[11];
  const int* send_idx = (const int*)d_in[12];
  const int* rec_idx  = (const int*)d_in[13];
  float* out = (float*)d_out;

  char* ws = (char*)d_ws;
  f16*    SA        = (f16*)   (ws + 0);                          // 1 MB
  f16*    RB        = (f16*)   (ws + (1u << 20));                 // 1 MB
  f16*    W2p       = (f16*)   (ws + (2u << 20));                 // 512 KB
  float*  agg       = (float*) (ws + (2u << 20) + (512u << 10));  // 512 KB
  int*    hist_part = (int*)   (ws + (3u << 20));                 // 128 KB
  int*    seg       = (int*)   (ws + (3u << 20) + (128u << 10));  // 4 KB
  int*    base      = (int*)   (ws + (3u << 20) + (132u << 10));  // 128 KB
  int*    ssend     = (int*)   (ws + (3u << 20) + (512u << 10));  // 1 MB
  float2* srel      = (float2*)(ws + (4u << 20) + (512u << 10));  // 2 MB  (total 6.5 MB)

  k_prep    <<<dim3(448), dim3(256),  0, stream>>>(inputs, W1, b1, W2, rec_idx, SA, RB, W2p, hist_part);
  k_scan    <<<dim3(1),   dim3(512),  0, stream>>>(hist_part, seg, base);
  k_scatter3<<<dim3(64),  dim3(1024), 0, stream>>>(rec_idx, send_idx, rel, base, ssend, srel);
  k_edges   <<<dim3(512), dim3(256),  0, stream>>>(SA, RB, W2p, b2, ssend, srel, seg, agg);
  k_out_mlp <<<dim3(256), dim3(256),  0, stream>>>(agg, Wo1, bo1, Wo2, bo2, Wo3, bo3, out);
}

// Round 6
// 380.624 us; speedup vs baseline: 1.0097x; 1.0097x over previous
//
#include <hip/hip_runtime.h>

#define C_N   512
#define E_N   261632

typedef _Float16 f16;
typedef _Float16 f16x8_t __attribute__((ext_vector_type(8)));
typedef float    f32x16_t __attribute__((ext_vector_type(16)));

// ---------------- fused prep: precompute SA/RB + pack W2 + hist partials ----------------
__global__ __launch_bounds__(256) void k_prep(const float* __restrict__ inputs,
    const float* __restrict__ W1, const float* __restrict__ b1,
    const float* __restrict__ W2, const int* __restrict__ rec,
    f16* __restrict__ SA, f16* __restrict__ RB, f16* __restrict__ W2p,
    int* __restrict__ hist_part)
{
  int bid = blockIdx.x;
  if (bid < 256) {
    int t  = bid >> 7;
    int c0 = (bid & 127) * 4;
    __shared__ float xs[4][256];
    for (int i = threadIdx.x; i < 1024; i += 256)
      xs[i >> 8][i & 255] = inputs[(size_t)(c0 + (i >> 8)) * 256 + (i & 255)];
    __syncthreads();
    const float* W1t = W1 + (size_t)t * 512 * 512;
    int h0 = threadIdx.x;
    float sa[2][4] = {{0.f}}, rbv[2][4] = {{0.f}};
    for (int d = 0; d < 256; d++) {
      float wt0 = W1t[d * 512 + h0];
      float wt1 = W1t[d * 512 + h0 + 256];
      float wb0 = W1t[(256 + d) * 512 + h0];
      float wb1 = W1t[(256 + d) * 512 + h0 + 256];
      #pragma unroll
      for (int r = 0; r < 4; r++) {
        float x = xs[r][d];
        sa[0][r]  += x * wt0; sa[1][r]  += x * wt1;
        rbv[0][r] += x * wb0; rbv[1][r] += x * wb1;
      }
    }
    #pragma unroll
    for (int hh = 0; hh < 2; hh++) {
      int h = h0 + hh * 256;
      float bb = b1[t * 512 + h];
      #pragma unroll
      for (int r = 0; r < 4; r++) {
        SA[((size_t)(t * 512 + c0 + r)) * 512 + h] = (f16)sa[hh][r];
        RB[((size_t)(t * 512 + c0 + r)) * 512 + h] = (f16)(rbv[hh][r] + bb);
      }
    }
  } else if (bid < 384) {
    // B-frag for mfma_f32_32x32x16_f16: n=lane&31, k=kc*16+(lane>>5)*8+j
    int gid  = (bid - 256) * 256 + threadIdx.x;   // 0..32767
    int lane = gid & 63;
    int ct   = (gid >> 6) & 7;
    int kc   = (gid >> 9) & 31;
    int t    = gid >> 14;
    int n    = ct * 32 + (lane & 31);
    int k0   = kc * 16 + (lane >> 5) * 8;
    const float* src = W2 + (size_t)t * 512 * 256;
    f16x8_t v;
    #pragma unroll
    for (int j = 0; j < 8; j++) v[j] = (f16)src[(size_t)(k0 + j) * 256 + n];
    *(f16x8_t*)(W2p + (size_t)gid * 8) = v;
  } else {
    int hb = bid - 384;                 // 0..63
    __shared__ int lh[512];
    for (int i = threadIdx.x; i < 512; i += 256) lh[i] = 0;
    __syncthreads();
    int e0 = hb * (E_N / 64);           // 4088 exactly
    for (int i = threadIdx.x; i < E_N / 64; i += 256)
      atomicAdd(&lh[rec[e0 + i]], 1);
    __syncthreads();
    for (int i = threadIdx.x; i < 512; i += 256)
      hist_part[hb * 512 + i] = lh[i];
  }
}

// ---------------- scan: totals + exclusive scan + per-scatter-block bases ----------------
__global__ void k_scan(const int* __restrict__ hist_part, int* __restrict__ seg,
                       int* __restrict__ base)
{
  __shared__ int s[512];
  int tid = threadIdx.x;
  int tot = 0;
  #pragma unroll 8
  for (int b = 0; b < 64; b++) tot += hist_part[b * 512 + tid];
  s[tid] = tot;
  __syncthreads();
  for (int off = 1; off < 512; off <<= 1) {
    int v = (tid >= off) ? s[tid - off] : 0;
    __syncthreads();
    s[tid] += v;
    __syncthreads();
  }
  int excl = s[tid] - tot;
  seg[tid] = excl;
  if (tid == 0) seg[512] = E_N;
  int run = excl;
  for (int b = 0; b < 64; b++) {
    base[b * 512 + tid] = run;
    run += hist_part[b * 512 + tid];
  }
}

// ---------------- scatter: no global atomics; writes pre-gathered metadata ----------------
__global__ __launch_bounds__(1024) void k_scatter3(const int* __restrict__ rec,
    const int* __restrict__ send, const float* __restrict__ rel,
    const int* __restrict__ base, int* __restrict__ ssend, float2* __restrict__ srel)
{
  __shared__ int lh[512];
  __shared__ int lb[512];
  int b = blockIdx.x;
  int e0 = b * (E_N / 64);   // 4088 exactly
  for (int i = threadIdx.x; i < 512; i += 1024) { lh[i] = 0; lb[i] = base[b * 512 + i]; }
  __syncthreads();
  for (int i = threadIdx.x; i < E_N / 64; i += 1024) {
    int e = e0 + i;
    int r = rec[e];
    int p = lb[r] + atomicAdd(&lh[r], 1);
    ssend[p] = send[e];
    srel[p]  = make_float2(rel[2 * (size_t)e], rel[2 * (size_t)e + 1]);
  }
}

// ---------------- K5: per-receiver edge MLP + aggregation (32x32x16, depth-4 B pipe) ----------------
#define H1S 520   // f16 elems per h1 row: 512 + 8 pad (conflict-free, measured 0)

__global__ __launch_bounds__(256, 2) void k_edges(
    const f16* __restrict__ SA, const f16* __restrict__ RB,
    const f16* __restrict__ W2p, const float* __restrict__ b2,
    const int* __restrict__ ssend, const float2* __restrict__ srel,
    const int* __restrict__ seg, float* __restrict__ agg)
{
  __shared__ f16   h1[64 * H1S];      // 66560 B
  __shared__ f16   rbs[2][512];       // 2048 B
  __shared__ float b2s[2][256];       // 2048 B
  __shared__ float aggL[256];         // 1024 B
  __shared__ float relv2[2][64][2];   // 1024 B
  __shared__ int   sends2[2][64];     // 512 B

  int c    = blockIdx.x;
  int tid  = threadIdx.x;             // 0..255
  int lane = tid & 63;
  int w    = tid >> 6;                // wave 0..3 -> col tiles 2w, 2w+1 (of 32)
  int hlf  = lane >> 5;               // 0..1
  int l31  = lane & 31;
  int q    = tid & 63;                // 16B chunk index in a 512-f16 row
  int rb0  = tid >> 6;                // gather/build base row: rows rb0 + 4j, j 0..15

  if (tid < 128) {
    int t = tid >> 6, qq = tid & 63;
    *(f16x8_t*)&rbs[t][qq * 8] = *(const f16x8_t*)&RB[((size_t)(t * 512 + c)) * 512 + qq * 8];
  }
  aggL[tid] = 0.0f;
  { int t = tid >> 7, col = tid & 255; b2s[t][col] = b2[t * 256 + col]; }
  { int t2 = (tid >> 7) ^ 1, col = tid & 255; b2s[t2][col] = b2[t2 * 256 + col]; }

  int s0 = seg[c], s1 = seg[c + 1];
  int nt = (s1 - s0 + 63) >> 6;

  if (nt > 0 && tid < 64) {
    int pos = s0 + tid;
    if (pos < s1) {
      sends2[0][tid] = ssend[pos];
      float2 rr = srel[pos];
      relv2[0][tid][0] = rr.x;
      relv2[0][tid][1] = rr.y;
    } else {
      sends2[0][tid] = 0; relv2[0][tid][0] = 0.f; relv2[0][tid][1] = 0.f;
    }
  }
  __syncthreads();

  f16x8_t g[16];
  const f16x8_t* SAc = (const f16x8_t*)SA;   // row r of type t at chunk (t*512+r)*64
  const f16x8_t* Bp  = (const f16x8_t*)W2p;

  if (nt > 0) {
    #pragma unroll
    for (int j = 0; j < 16; j++)
      g[j] = SAc[(size_t)sends2[0][rb0 + 4 * j] * 64 + q];
  }

  for (int ph = 0; ph < 2 * nt; ph++) {
    int ti  = ph >> 1;
    int t   = ph & 1;
    int cb  = ti & 1;
    int nb  = cb ^ 1;
    bool more = (ti + 1 < nt);

    // ---- build h1 = relu(SA[t][send] + RB[t][c]) from prefetched g ----
    {
      f16x8_t rbq = *(const f16x8_t*)&rbs[t][q * 8];
      #pragma unroll
      for (int j = 0; j < 16; j++) {
        int row = rb0 + 4 * j;
        f16x8_t hv;
        #pragma unroll
        for (int e = 0; e < 8; e++) {
          f16 v = (f16)(g[j][e] + rbq[e]);
          hv[e] = (v > (f16)0.0f) ? v : (f16)0.0f;
        }
        *(f16x8_t*)&h1[row * H1S + q * 8] = hv;
      }
    }
    __syncthreads();

    if (t == 0 && more && tid < 64) {
      int pos = s0 + (ti + 1) * 64 + tid;
      if (pos < s1) {
        sends2[nb][tid] = ssend[pos];
        float2 rr = srel[pos];
        relv2[nb][tid][0] = rr.x;
        relv2[nb][tid][1] = rr.y;
      } else {
        sends2[nb][tid] = 0; relv2[nb][tid][0] = 0.f; relv2[nb][tid][1] = 0.f;
      }
    }

    // ---- GEMM: msg[64,256] = h1 @ W2[t], 32x32x16 MFMA, depth-4 B prefetch ----
    f32x16_t acc[2][2];
    #pragma unroll
    for (int rt = 0; rt < 2; rt++)
      #pragma unroll
      for (int ctl = 0; ctl < 2; ctl++)
        #pragma unroll
        for (int r = 0; r < 16; r++) acc[rt][ctl][r] = 0.f;

    f16x8_t bb[4][2];
    #pragma unroll
    for (int d = 0; d < 4; d++)
      #pragma unroll
      for (int ctl = 0; ctl < 2; ctl++)
        bb[d][ctl] = Bp[(size_t)(((t * 32 + d) * 8 + (2 * w + ctl)) * 64 + lane)];

    // cross-phase gather issued after the initial B batch (FIFO: early B waits
    // don't force gather retirement; in-loop B waits at kc>=4 give gathers
    // >=4 kc of flight time)
    if (t == 0) {
      #pragma unroll
      for (int j = 0; j < 16; j++)
        g[j] = SAc[(size_t)(512 + sends2[cb][rb0 + 4 * j]) * 64 + q];
    } else if (more) {
      #pragma unroll
      for (int j = 0; j < 16; j++)
        g[j] = SAc[(size_t)sends2[nb][rb0 + 4 * j] * 64 + q];
    }

    for (int kc = 0; kc < 32; kc++) {
      int pb = kc & 3;
      #pragma unroll
      for (int rt = 0; rt < 2; rt++) {
        f16x8_t af = *(const f16x8_t*)&h1[(rt * 32 + l31) * H1S + kc * 16 + hlf * 8];
        #pragma unroll
        for (int ctl = 0; ctl < 2; ctl++)
          acc[rt][ctl] = __builtin_amdgcn_mfma_f32_32x32x16_f16(af, bb[pb][ctl], acc[rt][ctl], 0, 0, 0);
      }
      if (kc + 4 < 32) {
        #pragma unroll
        for (int ctl = 0; ctl < 2; ctl++)
          bb[pb][ctl] = Bp[(size_t)(((t * 32 + kc + 4) * 8 + (2 * w + ctl)) * 64 + lane)];
      }
    }

    // ---- epilogue: +b2, relu, *rel_type, reduce rows -> aggL ----
    // C/D 32x32: col = lane&31, row = (reg&3) + 8*(reg>>2) + 4*(lane>>5)
    #pragma unroll
    for (int ctl = 0; ctl < 2; ctl++) {
      int col = (2 * w + ctl) * 32 + l31;
      float b2c = b2s[t][col];
      float csum = 0.0f;
      #pragma unroll
      for (int rt = 0; rt < 2; rt++)
        #pragma unroll
        for (int r = 0; r < 16; r++) {
          int row = rt * 32 + (r & 3) + 8 * (r >> 2) + 4 * hlf;
          float v = fmaxf(acc[rt][ctl][r] + b2c, 0.0f);
          csum += v * relv2[cb][row][t];
        }
      csum += __shfl_xor(csum, 32, 64);
      if (hlf == 0) aggL[col] += csum;   // waves own disjoint col ranges
    }
    __syncthreads();
  }

  agg[(size_t)c * 256 + tid] = aggL[tid];
}

// ---------------- K6: output MLP (2 rows per block, fp32) ----------------
__global__ __launch_bounds__(256) void k_out_mlp(const float* __restrict__ agg,
    const float* __restrict__ Wo1, const float* __restrict__ bo1,
    const float* __restrict__ Wo2, const float* __restrict__ bo2,
    const float* __restrict__ Wo3, const float* __restrict__ bo3,
    float* __restrict__ out)
{
  __shared__ float xs[2][256];
  __shared__ float h1s[2][512];
  __shared__ float h2s[2][512];
  int tid = threadIdx.x;
  int c0 = blockIdx.x * 2;
  for (int i = tid; i < 512; i += 256)
    xs[i >> 8][i & 255] = agg[(size_t)(c0 + (i >> 8)) * 256 + (i & 255)];
  __syncthreads();
  #pragma unroll
  for (int hh = 0; hh < 2; hh++) {
    int h = tid + hh * 256;
    float a0 = 0.f, a1 = 0.f;
    for (int m = 0; m < 256; m++) {
      float wv = Wo1[m * 512 + h];
      a0 += xs[0][m] * wv;
      a1 += xs[1][m] * wv;
    }
    float bb = bo1[h];
    h1s[0][h] = fmaxf(a0 + bb, 0.f);
    h1s[1][h] = fmaxf(a1 + bb, 0.f);
  }
  __syncthreads();
  #pragma unroll
  for (int hh = 0; hh < 2; hh++) {
    int h = tid + hh * 256;
    float a0 = 0.f, a1 = 0.f;
    for (int m = 0; m < 512; m++) {
      float wv = Wo2[m * 512 + h];
      a0 += h1s[0][m] * wv;
      a1 += h1s[1][m] * wv;
    }
    float bb = bo2[h];
    h2s[0][h] = fmaxf(a0 + bb, 0.f);
    h2s[1][h] = fmaxf(a1 + bb, 0.f);
  }
  __syncthreads();
  {
    int d = tid;
    float a0 = 0.f, a1 = 0.f;
    for (int m = 0; m < 512; m++) {
      float wv = Wo3[m * 256 + d];
      a0 += h2s[0][m] * wv;
      a1 += h2s[1][m] * wv;
    }
    out[(size_t)c0 * 256 + d]       = a0 + bo3[d];
    out[((size_t)c0 + 1) * 256 + d] = a1 + bo3[d];
  }
}

// ---------------- launcher ----------------
extern "C" void kernel_launch(void* const* d_in, const int* in_sizes, int n_in,
                              void* d_out, int out_size, void* d_ws, size_t ws_size,
                              hipStream_t stream)
{
  (void)in_sizes; (void)n_in; (void)out_size; (void)ws_size;
  const float* inputs = (const float*)d_in[0];
  const float* rel    = (const float*)d_in[1];
  const float* W1     = (const float*)d_in[2];
  const float* b1     = (const float*)d_in[3];
  const float* W2     = (const float*)d_in[4];
  const float* b2     = (const float*)d_in[5];
  const float* Wo1    = (const float*)d_in[6];
  const float* bo1    = (const float*)d_in[7];
  const float* Wo2    = (const float*)d_in[8];
  const float* bo2    = (const float*)d_in[9];
  const float* Wo3    = (const float*)d_in[10];
  const float* bo3    = (const float*)d_in[11];
  const int* send_idx = (const int*)d_in[12];
  const int* rec_idx  = (const int*)d_in[13];
  float* out = (float*)d_out;

  char* ws = (char*)d_ws;
  f16*    SA        = (f16*)   (ws + 0);                          // 1 MB
  f16*    RB        = (f16*)   (ws + (1u << 20));                 // 1 MB
  f16*    W2p       = (f16*)   (ws + (2u << 20));                 // 512 KB
  float*  agg       = (float*) (ws + (2u << 20) + (512u << 10));  // 512 KB
  int*    hist_part = (int*)   (ws + (3u << 20));                 // 128 KB
  int*    seg       = (int*)   (ws + (3u << 20) + (128u << 10));  // 4 KB
  int*    base      = (int*)   (ws + (3u << 20) + (132u << 10));  // 128 KB
  int*    ssend     = (int*)   (ws + (3u << 20) + (512u << 10));  // 1 MB
  float2* srel      = (float2*)(ws + (4u << 20) + (512u << 10));  // 2 MB  (total 6.5 MB)

  k_prep    <<<dim3(448), dim3(256),  0, stream>>>(inputs, W1, b1, W2, rec_idx, SA, RB, W2p, hist_part);
  k_scan    <<<dim3(1),   dim3(512),  0, stream>>>(hist_part, seg, base);
  k_scatter3<<<dim3(64),  dim3(1024), 0, stream>>>(rec_idx, send_idx, rel, base, ssend, srel);
  k_edges   <<<dim3(512), dim3(256),  0, stream>>>(SA, RB, W2p, b2, ssend, srel, seg, agg);
  k_out_mlp <<<dim3(256), dim3(256),  0, stream>>>(agg, Wo1, bo1, Wo2, bo2, Wo3, bo3, out);
}

// Round 7
// 337.563 us; speedup vs baseline: 1.1385x; 1.1276x over previous
//
#include <hip/hip_runtime.h>

#define C_N   512
#define E_N   261632

typedef _Float16 f16;
typedef _Float16 f16x8_t __attribute__((ext_vector_type(8)));
typedef float    f32x16_t __attribute__((ext_vector_type(16)));

// ---------------- fused prep ----------------
// [0,256): SA/RB  [256,384): W2 pack  [384,448): hist  [448,512): Wo1 pack
// [512,640): Wo2 pack  [640,704): Wo3 pack
__global__ __launch_bounds__(256) void k_prep(const float* __restrict__ inputs,
    const float* __restrict__ W1, const float* __restrict__ b1,
    const float* __restrict__ W2, const int* __restrict__ rec,
    const float* __restrict__ Wo1, const float* __restrict__ Wo2, const float* __restrict__ Wo3,
    f16* __restrict__ SA, f16* __restrict__ RB, f16* __restrict__ W2p,
    f16* __restrict__ Wo1p, f16* __restrict__ Wo2p, f16* __restrict__ Wo3p,
    int* __restrict__ hist_part)
{
  int bid = blockIdx.x;
  if (bid < 256) {
    int t  = bid >> 7;
    int c0 = (bid & 127) * 4;
    __shared__ float xs[4][256];
    for (int i = threadIdx.x; i < 1024; i += 256)
      xs[i >> 8][i & 255] = inputs[(size_t)(c0 + (i >> 8)) * 256 + (i & 255)];
    __syncthreads();
    const float* W1t = W1 + (size_t)t * 512 * 512;
    int h0 = threadIdx.x;
    float sa[2][4] = {{0.f}}, rbv[2][4] = {{0.f}};
    for (int d = 0; d < 256; d++) {
      float wt0 = W1t[d * 512 + h0];
      float wt1 = W1t[d * 512 + h0 + 256];
      float wb0 = W1t[(256 + d) * 512 + h0];
      float wb1 = W1t[(256 + d) * 512 + h0 + 256];
      #pragma unroll
      for (int r = 0; r < 4; r++) {
        float x = xs[r][d];
        sa[0][r]  += x * wt0; sa[1][r]  += x * wt1;
        rbv[0][r] += x * wb0; rbv[1][r] += x * wb1;
      }
    }
    #pragma unroll
    for (int hh = 0; hh < 2; hh++) {
      int h = h0 + hh * 256;
      float bb = b1[t * 512 + h];
      #pragma unroll
      for (int r = 0; r < 4; r++) {
        SA[((size_t)(t * 512 + c0 + r)) * 512 + h] = (f16)sa[hh][r];
        RB[((size_t)(t * 512 + c0 + r)) * 512 + h] = (f16)(rbv[hh][r] + bb);
      }
    }
  } else if (bid < 384) {
    int gid  = (bid - 256) * 256 + threadIdx.x;   // 0..32767
    int lane = gid & 63;
    int ct   = (gid >> 6) & 7;
    int kc   = (gid >> 9) & 31;
    int t    = gid >> 14;
    int n    = ct * 32 + (lane & 31);
    int k0   = kc * 16 + (lane >> 5) * 8;
    const float* src = W2 + (size_t)t * 512 * 256;
    f16x8_t v;
    #pragma unroll
    for (int j = 0; j < 8; j++) v[j] = (f16)src[(size_t)(k0 + j) * 256 + n];
    *(f16x8_t*)(W2p + (size_t)gid * 8) = v;
  } else if (bid < 448) {
    int hb = bid - 384;
    __shared__ int lh[512];
    for (int i = threadIdx.x; i < 512; i += 256) lh[i] = 0;
    __syncthreads();
    int e0 = hb * (E_N / 64);
    for (int i = threadIdx.x; i < E_N / 64; i += 256)
      atomicAdd(&lh[rec[e0 + i]], 1);
    __syncthreads();
    for (int i = threadIdx.x; i < 512; i += 256)
      hist_part[hb * 512 + i] = lh[i];
  } else if (bid < 512) {
    int gid  = (bid - 448) * 256 + threadIdx.x;   // 0..16383
    int lane = gid & 63;
    int ct   = (gid >> 6) & 15;
    int kc   = gid >> 10;                          // 0..15
    int n    = ct * 32 + (lane & 31);
    int k0   = kc * 16 + (lane >> 5) * 8;
    f16x8_t v;
    #pragma unroll
    for (int j = 0; j < 8; j++) v[j] = (f16)Wo1[(size_t)(k0 + j) * 512 + n];
    *(f16x8_t*)(Wo1p + (size_t)gid * 8) = v;
  } else if (bid < 640) {
    int gid  = (bid - 512) * 256 + threadIdx.x;   // 0..32767
    int lane = gid & 63;
    int ct   = (gid >> 6) & 15;
    int kc   = gid >> 10;                          // 0..31
    int n    = ct * 32 + (lane & 31);
    int k0   = kc * 16 + (lane >> 5) * 8;
    f16x8_t v;
    #pragma unroll
    for (int j = 0; j < 8; j++) v[j] = (f16)Wo2[(size_t)(k0 + j) * 512 + n];
    *(f16x8_t*)(Wo2p + (size_t)gid * 8) = v;
  } else {
    int gid  = (bid - 640) * 256 + threadIdx.x;   // 0..16383
    int lane = gid & 63;
    int ct   = (gid >> 6) & 7;
    int kc   = gid >> 9;                           // 0..31
    int n    = ct * 32 + (lane & 31);
    int k0   = kc * 16 + (lane >> 5) * 8;
    f16x8_t v;
    #pragma unroll
    for (int j = 0; j < 8; j++) v[j] = (f16)Wo3[(size_t)(k0 + j) * 256 + n];
    *(f16x8_t*)(Wo3p + (size_t)gid * 8) = v;
  }
}

// ---------------- scan ----------------
__global__ void k_scan(const int* __restrict__ hist_part, int* __restrict__ seg,
                       int* __restrict__ base)
{
  __shared__ int s[512];
  int tid = threadIdx.x;
  int tot = 0;
  #pragma unroll 8
  for (int b = 0; b < 64; b++) tot += hist_part[b * 512 + tid];
  s[tid] = tot;
  __syncthreads();
  for (int off = 1; off < 512; off <<= 1) {
    int v = (tid >= off) ? s[tid - off] : 0;
    __syncthreads();
    s[tid] += v;
    __syncthreads();
  }
  int excl = s[tid] - tot;
  seg[tid] = excl;
  if (tid == 0) seg[512] = E_N;
  int run = excl;
  for (int b = 0; b < 64; b++) {
    base[b * 512 + tid] = run;
    run += hist_part[b * 512 + tid];
  }
}

// ---------------- scatter ----------------
__global__ __launch_bounds__(1024) void k_scatter3(const int* __restrict__ rec,
    const int* __restrict__ send, const float* __restrict__ rel,
    const int* __restrict__ base, int* __restrict__ ssend, float2* __restrict__ srel)
{
  __shared__ int lh[512];
  __shared__ int lb[512];
  int b = blockIdx.x;
  int e0 = b * (E_N / 64);
  for (int i = threadIdx.x; i < 512; i += 1024) { lh[i] = 0; lb[i] = base[b * 512 + i]; }
  __syncthreads();
  for (int i = threadIdx.x; i < E_N / 64; i += 1024) {
    int e = e0 + i;
    int r = rec[e];
    int p = lb[r] + atomicAdd(&lh[r], 1);
    ssend[p] = send[e];
    srel[p]  = make_float2(rel[2 * (size_t)e], rel[2 * (size_t)e + 1]);
  }
}

// ---------------- K5: edge MLP + aggregation (512 thr, 32x32, 2rt x 1ct/wave) ----------------
#define H1S 520

__global__ __launch_bounds__(512, 4) void k_edges(
    const f16* __restrict__ SA, const f16* __restrict__ RB,
    const f16* __restrict__ W2p, const float* __restrict__ b2,
    const int* __restrict__ ssend, const float2* __restrict__ srel,
    const int* __restrict__ seg, float* __restrict__ agg)
{
  __shared__ f16   h1[64 * H1S];
  __shared__ f16   rbs[2][512];
  __shared__ float b2s[2][256];
  __shared__ float aggL[256];
  __shared__ float relv2[2][64][2];
  __shared__ int   sends2[2][64];

  int c    = blockIdx.x;
  int tid  = threadIdx.x;             // 0..511
  int lane = tid & 63;
  int w    = tid >> 6;                // wave 0..7 -> col tile w (32 cols)
  int hlf  = lane >> 5;
  int l31  = lane & 31;
  int q    = tid & 63;
  int rb0  = tid >> 6;                // rows rb0 + 8j, j=0..7

  if (tid < 128) {
    int t = tid >> 6, qq = tid & 63;
    *(f16x8_t*)&rbs[t][qq * 8] = *(const f16x8_t*)&RB[((size_t)(t * 512 + c)) * 512 + qq * 8];
  }
  if (tid < 256) aggL[tid] = 0.0f;
  if (tid < 512) { int t = (tid >> 8) & 1, col = tid & 255; b2s[t][col] = b2[t * 256 + col]; }

  int s0 = seg[c], s1 = seg[c + 1];
  int nt = (s1 - s0 + 63) >> 6;

  if (nt > 0 && tid < 64) {
    int pos = s0 + tid;
    if (pos < s1) {
      sends2[0][tid] = ssend[pos];
      float2 rr = srel[pos];
      relv2[0][tid][0] = rr.x;
      relv2[0][tid][1] = rr.y;
    } else {
      sends2[0][tid] = 0; relv2[0][tid][0] = 0.f; relv2[0][tid][1] = 0.f;
    }
  }
  __syncthreads();

  f16x8_t g[8];
  const f16x8_t* SAc = (const f16x8_t*)SA;
  const f16x8_t* Bp  = (const f16x8_t*)W2p;

  if (nt > 0) {
    #pragma unroll
    for (int j = 0; j < 8; j++)
      g[j] = SAc[(size_t)sends2[0][rb0 + 8 * j] * 64 + q];
  }

  for (int ph = 0; ph < 2 * nt; ph++) {
    int ti  = ph >> 1;
    int t   = ph & 1;
    int cb  = ti & 1;
    int nb  = cb ^ 1;
    bool more = (ti + 1 < nt);

    // build h1 = relu(SA + RB)
    {
      f16x8_t rbq = *(const f16x8_t*)&rbs[t][q * 8];
      #pragma unroll
      for (int j = 0; j < 8; j++) {
        int row = rb0 + 8 * j;
        f16x8_t hv;
        #pragma unroll
        for (int e = 0; e < 8; e++) {
          f16 v = (f16)(g[j][e] + rbq[e]);
          hv[e] = (v > (f16)0.0f) ? v : (f16)0.0f;
        }
        *(f16x8_t*)&h1[row * H1S + q * 8] = hv;
      }
    }
    __syncthreads();

    if (t == 0 && more && tid < 64) {
      int pos = s0 + (ti + 1) * 64 + tid;
      if (pos < s1) {
        sends2[nb][tid] = ssend[pos];
        float2 rr = srel[pos];
        relv2[nb][tid][0] = rr.x;
        relv2[nb][tid][1] = rr.y;
      } else {
        sends2[nb][tid] = 0; relv2[nb][tid][0] = 0.f; relv2[nb][tid][1] = 0.f;
      }
    }

    f32x16_t acc[2];
    #pragma unroll
    for (int rt = 0; rt < 2; rt++)
      #pragma unroll
      for (int r = 0; r < 16; r++) acc[rt][r] = 0.f;

    f16x8_t bb[2];
    bb[0] = Bp[(size_t)(((t * 32 + 0) * 8 + w) * 64 + lane)];
    bb[1] = Bp[(size_t)(((t * 32 + 1) * 8 + w) * 64 + lane)];

    // cross-phase gather after initial B loads (FIFO: stays in flight)
    if (t == 0) {
      #pragma unroll
      for (int j = 0; j < 8; j++)
        g[j] = SAc[(size_t)(512 + sends2[cb][rb0 + 8 * j]) * 64 + q];
    } else if (more) {
      #pragma unroll
      for (int j = 0; j < 8; j++)
        g[j] = SAc[(size_t)sends2[nb][rb0 + 8 * j] * 64 + q];
    }

    for (int kc = 0; kc < 32; kc++) {
      int pb = kc & 1;
      f16x8_t af0 = *(const f16x8_t*)&h1[(l31) * H1S + kc * 16 + hlf * 8];
      acc[0] = __builtin_amdgcn_mfma_f32_32x32x16_f16(af0, bb[pb], acc[0], 0, 0, 0);
      f16x8_t af1 = *(const f16x8_t*)&h1[(32 + l31) * H1S + kc * 16 + hlf * 8];
      acc[1] = __builtin_amdgcn_mfma_f32_32x32x16_f16(af1, bb[pb], acc[1], 0, 0, 0);
      if (kc + 2 < 32)
        bb[pb] = Bp[(size_t)(((t * 32 + kc + 2) * 8 + w) * 64 + lane)];
    }

    // epilogue
    {
      int col = w * 32 + l31;
      float b2c = b2s[t][col];
      float csum = 0.0f;
      #pragma unroll
      for (int rt = 0; rt < 2; rt++)
        #pragma unroll
        for (int r = 0; r < 16; r++) {
          int row = rt * 32 + (r & 3) + 8 * (r >> 2) + 4 * hlf;
          float v = fmaxf(acc[rt][r] + b2c, 0.0f);
          csum += v * relv2[cb][row][t];
        }
      csum += __shfl_xor(csum, 32, 64);
      if (hlf == 0) aggL[col] += csum;
    }
    __syncthreads();
  }

  if (tid < 256) agg[(size_t)c * 256 + tid] = aggL[tid];
}

// ---------------- output MLP: three MFMA layer kernels (no LDS, no barriers) ----------------
// layer 1: h1o[512,512] = relu(agg[512,256] @ Wo1 + bo1), A fp32 -> f16 in regs
__global__ __launch_bounds__(256) void k_omlp1(const float* __restrict__ agg,
    const f16* __restrict__ Wo1p, const float* __restrict__ bo1, f16* __restrict__ h1o)
{
  int tid = threadIdx.x, lane = tid & 63, w = tid >> 6;
  int hlf = lane >> 5, l31 = lane & 31;
  int br = blockIdx.x, bc = blockIdx.y;
  f32x16_t acc[2][2];
  #pragma unroll
  for (int rt = 0; rt < 2; rt++)
    #pragma unroll
    for (int ctl = 0; ctl < 2; ctl++)
      #pragma unroll
      for (int r = 0; r < 16; r++) acc[rt][ctl][r] = 0.f;
  for (int kc = 0; kc < 16; kc++) {
    f16x8_t af[2];
    #pragma unroll
    for (int rt = 0; rt < 2; rt++) {
      const float4* p = (const float4*)&agg[(size_t)(br * 64 + rt * 32 + l31) * 256 + kc * 16 + hlf * 8];
      float4 u0 = p[0], u1 = p[1];
      af[rt] = (f16x8_t){(f16)u0.x, (f16)u0.y, (f16)u0.z, (f16)u0.w,
                         (f16)u1.x, (f16)u1.y, (f16)u1.z, (f16)u1.w};
    }
    #pragma unroll
    for (int ctl = 0; ctl < 2; ctl++) {
      f16x8_t bfr = *(const f16x8_t*)&Wo1p[((size_t)(kc * 16 + bc * 8 + 2 * w + ctl) * 64 + lane) * 8];
      #pragma unroll
      for (int rt = 0; rt < 2; rt++)
        acc[rt][ctl] = __builtin_amdgcn_mfma_f32_32x32x16_f16(af[rt], bfr, acc[rt][ctl], 0, 0, 0);
    }
  }
  #pragma unroll
  for (int ctl = 0; ctl < 2; ctl++) {
    int col = bc * 256 + (2 * w + ctl) * 32 + l31;
    float bias = bo1[col];
    #pragma unroll
    for (int rt = 0; rt < 2; rt++)
      #pragma unroll
      for (int r = 0; r < 16; r++) {
        int row = br * 64 + rt * 32 + (r & 3) + 8 * (r >> 2) + 4 * hlf;
        h1o[(size_t)row * 512 + col] = (f16)fmaxf(acc[rt][ctl][r] + bias, 0.f);
      }
  }
}

// layer 2: h2o[512,512] = relu(h1o @ Wo2 + bo2), f16 A direct
__global__ __launch_bounds__(256) void k_omlp2(const f16* __restrict__ h1o,
    const f16* __restrict__ Wo2p, const float* __restrict__ bo2, f16* __restrict__ h2o)
{
  int tid = threadIdx.x, lane = tid & 63, w = tid >> 6;
  int hlf = lane >> 5, l31 = lane & 31;
  int br = blockIdx.x, bc = blockIdx.y;
  f32x16_t acc[2][2];
  #pragma unroll
  for (int rt = 0; rt < 2; rt++)
    #pragma unroll
    for (int ctl = 0; ctl < 2; ctl++)
      #pragma unroll
      for (int r = 0; r < 16; r++) acc[rt][ctl][r] = 0.f;
  for (int kc = 0; kc < 32; kc++) {
    f16x8_t af[2];
    #pragma unroll
    for (int rt = 0; rt < 2; rt++)
      af[rt] = *(const f16x8_t*)&h1o[(size_t)(br * 64 + rt * 32 + l31) * 512 + kc * 16 + hlf * 8];
    #pragma unroll
    for (int ctl = 0; ctl < 2; ctl++) {
      f16x8_t bfr = *(const f16x8_t*)&Wo2p[((size_t)(kc * 16 + bc * 8 + 2 * w + ctl) * 64 + lane) * 8];
      #pragma unroll
      for (int rt = 0; rt < 2; rt++)
        acc[rt][ctl] = __builtin_amdgcn_mfma_f32_32x32x16_f16(af[rt], bfr, acc[rt][ctl], 0, 0, 0);
    }
  }
  #pragma unroll
  for (int ctl = 0; ctl < 2; ctl++) {
    int col = bc * 256 + (2 * w + ctl) * 32 + l31;
    float bias = bo2[col];
    #pragma unroll
    for (int rt = 0; rt < 2; rt++)
      #pragma unroll
      for (int r = 0; r < 16; r++) {
        int row = br * 64 + rt * 32 + (r & 3) + 8 * (r >> 2) + 4 * hlf;
        h2o[(size_t)row * 512 + col] = (f16)fmaxf(acc[rt][ctl][r] + bias, 0.f);
      }
  }
}

// layer 3: out[512,256] = h2o @ Wo3 + bo3 (fp32 out, no relu)
__global__ __launch_bounds__(256) void k_omlp3(const f16* __restrict__ h2o,
    const f16* __restrict__ Wo3p, const float* __restrict__ bo3, float* __restrict__ out)
{
  int tid = threadIdx.x, lane = tid & 63, w = tid >> 6;
  int hlf = lane >> 5, l31 = lane & 31;
  int br = blockIdx.x;
  f32x16_t acc[2][2];
  #pragma unroll
  for (int rt = 0; rt < 2; rt++)
    #pragma unroll
    for (int ctl = 0; ctl < 2; ctl++)
      #pragma unroll
      for (int r = 0; r < 16; r++) acc[rt][ctl][r] = 0.f;
  for (int kc = 0; kc < 32; kc++) {
    f16x8_t af[2];
    #pragma unroll
    for (int rt = 0; rt < 2; rt++)
      af[rt] = *(const f16x8_t*)&h2o[(size_t)(br * 64 + rt * 32 + l31) * 512 + kc * 16 + hlf * 8];
    #pragma unroll
    for (int ctl = 0; ctl < 2; ctl++) {
      f16x8_t bfr = *(const f16x8_t*)&Wo3p[((size_t)(kc * 8 + 2 * w + ctl) * 64 + lane) * 8];
      #pragma unroll
      for (int rt = 0; rt < 2; rt++)
        acc[rt][ctl] = __builtin_amdgcn_mfma_f32_32x32x16_f16(af[rt], bfr, acc[rt][ctl], 0, 0, 0);
    }
  }
  #pragma unroll
  for (int ctl = 0; ctl < 2; ctl++) {
    int col = (2 * w + ctl) * 32 + l31;
    float bias = bo3[col];
    #pragma unroll
    for (int rt = 0; rt < 2; rt++)
      #pragma unroll
      for (int r = 0; r < 16; r++) {
        int row = br * 64 + rt * 32 + (r & 3) + 8 * (r >> 2) + 4 * hlf;
        out[(size_t)row * 256 + col] = acc[rt][ctl][r] + bias;
      }
  }
}

// ---------------- launcher ----------------
extern "C" void kernel_launch(void* const* d_in, const int* in_sizes, int n_in,
                              void* d_out, int out_size, void* d_ws, size_t ws_size,
                              hipStream_t stream)
{
  (void)in_sizes; (void)n_in; (void)out_size; (void)ws_size;
  const float* inputs = (const float*)d_in[0];
  const float* rel    = (const float*)d_in[1];
  const float* W1     = (const float*)d_in[2];
  const float* b1     = (const float*)d_in[3];
  const float* W2     = (const float*)d_in[4];
  const float* b2     = (const float*)d_in[5];
  const float* Wo1    = (const float*)d_in[6];
  const float* bo1    = (const float*)d_in[7];
  const float* Wo2    = (const float*)d_in[8];
  const float* bo2    = (const float*)d_in[9];
  const float* Wo3    = (const float*)d_in[10];
  const float* bo3    = (const float*)d_in[11];
  const int* send_idx = (const int*)d_in[12];
  const int* rec_idx  = (const int*)d_in[13];
  float* out = (float*)d_out;

  char* ws = (char*)d_ws;
  f16*    SA        = (f16*)   (ws);                              // 1 MB
  f16*    RB        = (f16*)   (ws + (1u << 20));                 // 1 MB
  f16*    W2p       = (f16*)   (ws + (2u << 20));                 // 512 KB
  float*  agg       = (float*) (ws + (2560u << 10));              // 512 KB
  int*    hist_part = (int*)   (ws + (3u << 20));                 // 128 KB
  int*    seg       = (int*)   (ws + (3u << 20) + (128u << 10));  // 4 KB
  int*    base      = (int*)   (ws + (3u << 20) + (132u << 10));  // 128 KB
  int*    ssend     = (int*)   (ws + (3584u << 10));              // 1 MB
  float2* srel      = (float2*)(ws + (4608u << 10));              // 2 MB
  f16*    Wo1p      = (f16*)   (ws + (6656u << 10));              // 256 KB
  f16*    Wo2p      = (f16*)   (ws + (6912u << 10));              // 512 KB
  f16*    Wo3p      = (f16*)   (ws + (7424u << 10));              // 256 KB
  f16*    h1o       = (f16*)   (ws + (7680u << 10));              // 512 KB
  f16*    h2o       = (f16*)   (ws + (8192u << 10));              // 512 KB (total 8.5 MB)

  k_prep    <<<dim3(704), dim3(256),  0, stream>>>(inputs, W1, b1, W2, rec_idx,
                                                   Wo1, Wo2, Wo3,
                                                   SA, RB, W2p, Wo1p, Wo2p, Wo3p, hist_part);
  k_scan    <<<dim3(1),   dim3(512),  0, stream>>>(hist_part, seg, base);
  k_scatter3<<<dim3(64),  dim3(1024), 0, stream>>>(rec_idx, send_idx, rel, base, ssend, srel);
  k_edges   <<<dim3(512), dim3(512),  0, stream>>>(SA, RB, W2p, b2, ssend, srel, seg, agg);
  k_omlp1   <<<dim3(8,2), dim3(256),  0, stream>>>(agg, Wo1p, bo1, h1o);
  k_omlp2   <<<dim3(8,2), dim3(256),  0, stream>>>(h1o, Wo2p, bo2, h2o);
  k_omlp3   <<<dim3(8),   dim3(256),  0, stream>>>(h2o, Wo3p, bo3, out);
}